// Round 8
// baseline (238.126 us; speedup 1.0000x reference)
//
#include <hip/hip_runtime.h>

// Problem constants
#define ARW_N_NODES   100000
#define ARW_N_EDGES   3200000
#define ARW_N_WALKERS 400000
#define ARW_WLEN      8
#define ARW_LOUT      7
#define ARW_ROW_LEN   6000000           // N_EDGES + N_WALKERS*LOUT
#define ARW_OUT_ELEMS 18000000          // float32 output elements

// Sort geometry: 256 buckets of 392 rows (b = r/392); 3125 tiles of 1024 edges;
// thist does 5 tiles/block (625 blocks: full CU coverage + short write runs).
#define ARW_NB    256
#define ARW_RPB   392
#define ARW_NT    3125
#define ARW_TP    3136                 // padded row stride for Ht/Bt (t-contiguous)
#define ARW_TILE  1024
#define ARW_TPB   5                    // tiles per thist block (3125 = 625*5)

// Scratch inside d_out (18M floats = 72MB), int32 view; staged lifetimes:
//   Ht  @ [0, 802816)          histograms Ht[b][t] = HT + b*TP + t
//   Bt  @ [900000, 1702816)    bucket-LOCAL scan bases Bt[b][t] (exclusive, from 0)
//   tot @ [1750000, +256)      per-bucket totals (emitted by bscan2)
//   cb  @ [1760000, +256)      bucket exclusive bases (global)
//   pd  @ [1800000, 1900000)   packed (rowptr<<10 | deg), written by pass2
//   P   @ [6000000, 9200000)   packed partition (dead after pass2; walk's fused
//                              row1-copy overwrites it)
//   col_s @ [12000000, 15200000) (weights region; asm overwrites after walk)
// walk writes: targets [9200000,12000000), roots [3200000,6000000),
//              row1-originals [6000000,9200000).
// asm (last) writes [0,3200000) + [12000000,18000000).
#define ARW_HT    0
#define ARW_BT    900000
#define ARW_TOT   1750000
#define ARW_CB    1760000
#define ARW_PD    1800000
#define ARW_P     6000000
#define ARW_COLS  12000000

__global__ void AddRandomWalkEdge_16896401342869_kernel() {}

// ---------- 1. tile histogram, 5 tiles/block ----------
__global__ __launch_bounds__(1024) void arw16896_thist(const int* __restrict__ row,
                                                       int* __restrict__ s) {
    __shared__ int h[ARW_TPB * 256];
    int tid = threadIdx.x;
    for (int x = tid; x < ARW_TPB * 256; x += 1024) h[x] = 0;
    __syncthreads();
    int base_e = blockIdx.x * (ARW_TPB * ARW_TILE) + tid;
    #pragma unroll
    for (int j = 0; j < ARW_TPB; j++)
        atomicAdd(&h[j * 256 + (row[base_e + j * 1024] / ARW_RPB)], 1);
    __syncthreads();
    for (int x = tid; x < ARW_TPB * ARW_NB; x += 1024) {
        int b = x / ARW_TPB, j = x % ARW_TPB;
        s[ARW_HT + b * ARW_TP + blockIdx.x * ARW_TPB + j] = h[j * 256 + b];
    }
}

// ---------- 2a. per-bucket chunked exclusive scan (local, from 0) + total ----------
__global__ __launch_bounds__(1024) void arw16896_bscan2(int* __restrict__ s) {
    __shared__ int wsum[16];
    int b = blockIdx.x, tid = threadIdx.x, lane = tid & 63, wid = tid >> 6;
    int carry = 0;
    for (int c0 = 0; c0 < ARW_NT; c0 += 1024) {
        int t = c0 + tid;
        int v = (t < ARW_NT) ? s[ARW_HT + b * ARW_TP + t] : 0;
        int sv = v;
        #pragma unroll
        for (int off = 1; off < 64; off <<= 1) {
            int x = __shfl_up(sv, off, 64);
            if (lane >= off) sv += x;
        }
        if (lane == 63) wsum[wid] = sv;
        __syncthreads();
        int pre = 0, tot = 0;
        #pragma unroll
        for (int w = 0; w < 16; w++) {
            int x = wsum[w];
            if (w < wid) pre += x;
            tot += x;
        }
        if (t < ARW_NT) s[ARW_BT + b * ARW_TP + t] = carry + pre + sv - v;
        carry += tot;
        __syncthreads();
    }
    if (tid == 0) s[ARW_TOT + b] = carry;
}

// ---------- 2b. exclusive scan of 256 bucket totals (1 block) -> cb ----------
__global__ __launch_bounds__(256) void arw16896_bbase(int* __restrict__ s) {
    __shared__ int sm[256];
    int tid = threadIdx.x;
    int v = s[ARW_TOT + tid];
    sm[tid] = v;
    __syncthreads();
    for (int off = 1; off < 256; off <<= 1) {
        int x = 0;
        if (tid >= off) x = sm[tid - off];
        __syncthreads();
        sm[tid] += x;
        __syncthreads();
    }
    s[ARW_CB + tid] = sm[tid] - v;
}

// ---------- 3. stable partition into buckets (ballot multisplit, no atomics) ----------
__global__ __launch_bounds__(1024) void arw16896_part(const int* __restrict__ row,
                                                      const int* __restrict__ col,
                                                      int* __restrict__ s) {
    __shared__ unsigned W[16 * 256];
    int tid  = threadIdx.x;
    int wave = tid >> 6, lane = tid & 63;
    int e = blockIdx.x * ARW_TILE + tid;
    int r = row[e], cv = col[e];
    int b = r / ARW_RPB;                 // magic-mul division
    int lr = r - b * ARW_RPB;            // 9 bits (<392)
    W[tid] = 0; W[tid + 1024] = 0; W[tid + 2048] = 0; W[tid + 3072] = 0;
    __syncthreads();
    unsigned long long mask = ~0ULL;
    #pragma unroll
    for (int bit = 0; bit < 8; bit++) {
        unsigned long long bal = __ballot((b >> bit) & 1);
        mask &= ((b >> bit) & 1) ? bal : ~bal;
    }
    int rankw = __popcll(mask & ((1ULL << lane) - 1ULL));
    W[wave * 256 + b] = (unsigned)__popcll(mask);
    __syncthreads();
    int cross = 0;
    for (int w2 = 0; w2 < 16; w2++) {
        if (w2 >= wave) break;
        cross += (int)W[w2 * 256 + b];
    }
    int base = s[ARW_CB + b] + s[ARW_BT + b * ARW_TP + blockIdx.x];
    s[ARW_P + base + cross + rankw] = (lr << 17) | cv;   // pack(local_r, col)
}

// ---------- 4. per-bucket stable scatter: wave-private-counter counting sort ----------
// Each wave owns a CONTIGUOUS range of the bucket's (e-ordered) P list.
// Step 1: wave counts per-row edges into private column C[row][wave] via
//         ballot-match (leader-lane RMW; no atomics, no barriers).
// Step 2: deg = row-sum of C; 512-scan -> rowptr/pd; per-row scan across waves
//         -> cursor B[row][wave]. Cross-wave order paid ONCE (old: per chunk).
// Step 3: wave re-walks its range in order; leader bumps its private cursor;
//         lanes write col at base+rankw. Stable: lane order within wave,
//         B construction across waves.
__global__ __launch_bounds__(1024) void arw16896_pass2(int* __restrict__ s) {
    __shared__ unsigned short C[ARW_RPB * 16];   // 12.5 KB per-(row,wave) counts
    __shared__ int B[ARW_RPB * 16];              // 25 KB per-(row,wave) cursors
    __shared__ int hist[512], pref[512];
    int tid = threadIdx.x, lane = tid & 63, wave = tid >> 6;
    int b = blockIdx.x;
    int start = s[ARW_CB + b];
    int end   = (b == ARW_NB - 1) ? ARW_N_EDGES : s[ARW_CB + b + 1];
    int cnt = end - start;
    int rows0 = b * ARW_RPB;
    int nrows = ARW_N_NODES - rows0; if (nrows > ARW_RPB) nrows = ARW_RPB;
    int per  = (cnt + 15) >> 4;
    int wbeg = wave * per; if (wbeg > cnt) wbeg = cnt;
    int wend = wbeg + per; if (wend > cnt) wend = cnt;

    for (int x = tid; x < ARW_RPB * 16; x += 1024) C[x] = 0;
    if (tid < 512) hist[tid] = 0;
    __syncthreads();

    // Step 1: per-(wave,row) counts, in e-order
    for (int k = wbeg + lane; k < wend; k += 64) {
        unsigned lr = (unsigned)s[ARW_P + start + k] >> 17;
        unsigned long long mask = ~0ULL;
        #pragma unroll
        for (int bit = 0; bit < 9; bit++) {
            unsigned long long bal = __ballot((lr >> bit) & 1u);
            mask &= ((lr >> bit) & 1u) ? bal : ~bal;
        }
        mask &= __ballot(1);                     // clip to active lanes (lr==0 case)
        int leader = __ffsll(mask) - 1;
        if (lane == leader)
            C[lr * 16 + wave] = (unsigned short)(C[lr * 16 + wave] + __popcll(mask));
    }
    __syncthreads();

    // Step 2: deg, rowptr scan, pd, per-row cross-wave cursor bases
    if (tid < nrows) {
        int a = 0;
        #pragma unroll
        for (int w = 0; w < 16; w++) a += (int)C[tid * 16 + w];
        hist[tid] = a;
    }
    __syncthreads();
    if (tid < 512) pref[tid] = hist[tid];
    __syncthreads();
    for (int off = 1; off < 512; off <<= 1) {     // inclusive scan of hist
        int x = 0;
        if (tid < 512 && tid >= off) x = pref[tid - off];
        __syncthreads();
        if (tid < 512) pref[tid] += x;
        __syncthreads();
    }
    if (tid < nrows) {
        int rowbase = start + pref[tid] - hist[tid];
        // packed (rowptr<<10 | deg). rowptr < 3.2M (22 bits); deg Poisson(32) << 1023.
        s[ARW_PD + rows0 + tid] = (int)(((unsigned)rowbase << 10) | (unsigned)hist[tid]);
        int acc = rowbase;
        #pragma unroll
        for (int w = 0; w < 16; w++) { B[tid * 16 + w] = acc; acc += (int)C[tid * 16 + w]; }
    }
    __syncthreads();

    // Step 3: stable scatter via wave-private cursors (no atomics, no barriers)
    for (int k = wbeg + lane; k < wend; k += 64) {
        unsigned p = (unsigned)s[ARW_P + start + k];
        unsigned lr = p >> 17;
        unsigned long long mask = ~0ULL;
        #pragma unroll
        for (int bit = 0; bit < 9; bit++) {
            unsigned long long bal = __ballot((lr >> bit) & 1u);
            mask &= ((lr >> bit) & 1u) ? bal : ~bal;
        }
        mask &= __ballot(1);
        int leader = __ffsll(mask) - 1;
        int rankw = __popcll(mask & ((1ULL << lane) - 1ULL));
        int base = 0;
        if (lane == leader) {
            base = B[lr * 16 + wave];
            B[lr * 16 + wave] = base + __popcll(mask);
        }
        base = __shfl(base, leader, 64);
        s[ARW_COLS + base + rankw] = (int)(p & 0x1FFFFu);
    }
}

// ---------- 5. walks (256 thr) + fused streaming tail ----------
// Walk is miss-throughput bound (~36% HBM BW, VALU 3%): idle BW absorbs the
// row1-originals copy ([6M,9.2M), over dead P) and the roots fill ([3.2M,6M)).
__global__ __launch_bounds__(256) void arw16896_walk(const float* __restrict__ ru,
                                                     const int* __restrict__ ei,
                                                     const int* __restrict__ s,
                                                     float* __restrict__ o) {
    __shared__ float tg[4 * 256 * ARW_LOUT];   // 28 KB: 4 segments of 256x7
    int tid = threadIdx.x;
    int v = blockIdx.x * 256 + tid;
    if (v < ARW_N_NODES) {
        float uu[4][8];
        int cur[4];
        #pragma unroll
        for (int k = 0; k < 4; k++) {
            const float4* rp4 = (const float4*)(ru + (size_t)(v + k * ARW_N_NODES) * 8);
            float4 ra = rp4[0], rb = rp4[1];
            uu[k][0] = ra.x; uu[k][1] = ra.y; uu[k][2] = ra.z; uu[k][3] = ra.w;
            uu[k][4] = rb.x; uu[k][5] = rb.y; uu[k][6] = rb.z; uu[k][7] = rb.w;
        }
        // step 0: all 4 walkers share pd[v]; col loads hit the same row segment
        unsigned pd0 = (unsigned)s[ARW_PD + v];
        int d0  = (int)(pd0 & 1023u);
        int rp0 = (int)(pd0 >> 10);
        #pragma unroll
        for (int k = 0; k < 4; k++) {
            int off = (int)(uu[k][0] * (float)d0);   // f32 mul + trunc == reference
            if (off > d0 - 1) off = d0 - 1;
            int nxt = s[ARW_COLS + rp0 + off];       // off=-1 only if d0==0: in-bounds junk
            cur[k] = (d0 > 0) ? nxt : v;
        }
        // steps 1..7: 4 independent chains; batch the 4 pd loads, then 4 col loads
        #pragma unroll
        for (int t = 1; t < ARW_WLEN; t++) {
            unsigned pdk[4];
            #pragma unroll
            for (int k = 0; k < 4; k++) pdk[k] = (unsigned)s[ARW_PD + cur[k]];
            #pragma unroll
            for (int k = 0; k < 4; k++) {
                int d = (int)(pdk[k] & 1023u);
                int off = (int)(uu[k][t] * (float)d);
                if (off > d - 1) off = d - 1;        // d==0 -> off=-1, load stays in-bounds
                int nxt = s[ARW_COLS + (int)(pdk[k] >> 10) + off];
                cur[k] = (d > 0) ? nxt : cur[k];
                tg[k * (256 * ARW_LOUT) + tid * ARW_LOUT + (t - 1)] = (float)cur[k];
            }
        }
    }
    __syncthreads();
    int blkN = ARW_N_NODES - blockIdx.x * 256;
    if (blkN > 256) blkN = 256;
    int valid = blkN * ARW_LOUT;
    #pragma unroll
    for (int k = 0; k < 4; k++) {
        int base = ARW_ROW_LEN + ARW_N_EDGES +
                   (k * ARW_N_NODES + blockIdx.x * 256) * ARW_LOUT;
        for (int j = tid; j < valid; j += 256)
            o[base + j] = tg[k * (256 * ARW_LOUT) + j];
    }
    // fused streaming tail (grid-stride over all walk threads)
    int gid = blockIdx.x * 256 + tid;
    int stride = gridDim.x * 256;
    for (int i4 = gid; i4 < ARW_N_EDGES / 4; i4 += stride) {
        int4 r1 = ((const int4*)(ei + ARW_N_EDGES))[i4];
        ((float4*)(o + ARW_ROW_LEN))[i4] =
            make_float4((float)r1.x, (float)r1.y, (float)r1.z, (float)r1.w);
    }
    for (int i4 = gid; i4 < (ARW_N_WALKERS * ARW_LOUT) / 4; i4 += stride) {
        int i = i4 * 4;
        float4 r;
        r.x = (float)(((i    ) / ARW_LOUT) % ARW_N_NODES);
        r.y = (float)(((i + 1) / ARW_LOUT) % ARW_N_NODES);
        r.z = (float)(((i + 2) / ARW_LOUT) % ARW_N_NODES);
        r.w = (float)(((i + 3) / ARW_LOUT) % ARW_N_NODES);
        ((float4*)(o + ARW_N_EDGES))[i4] = r;
    }
}

// ---------- 6. remaining assembly: row0 originals + weights + ones ----------
__global__ __launch_bounds__(256) void arw16896_asm(const int* __restrict__ ei,
                                                    const float* __restrict__ wgt,
                                                    float* __restrict__ o) {
    int i4 = blockIdx.x * blockDim.x + threadIdx.x;
    if (i4 < ARW_N_EDGES / 4) {
        int4 r0 = ((const int4*)ei)[i4];
        float4 wv = ((const float4*)wgt)[i4];
        ((float4*)o)[i4] = make_float4((float)r0.x, (float)r0.y, (float)r0.z, (float)r0.w);
        ((float4*)(o + 2 * ARW_ROW_LEN))[i4] = wv;
    }
    if (i4 < (ARW_N_WALKERS * ARW_LOUT) / 4) {
        ((float4*)(o + 2 * ARW_ROW_LEN + ARW_N_EDGES))[i4] = make_float4(1.f, 1.f, 1.f, 1.f);
    }
}

extern "C" void kernel_launch(void* const* d_in, const int* in_sizes, int n_in,
                              void* d_out, int out_size, void* d_ws, size_t ws_size,
                              hipStream_t stream) {
    const int*   ei  = (const int*)d_in[0];
    const float* wgt = (const float*)d_in[1];
    const float* ru  = (const float*)d_in[2];
    int*   s = (int*)d_out;
    float* o = (float*)d_out;
    const int* row = ei;
    const int* col = ei + ARW_N_EDGES;

    arw16896_thist <<<ARW_NT / ARW_TPB, 1024, 0, stream>>>(row, s);
    arw16896_bscan2<<<ARW_NB, 1024, 0, stream>>>(s);
    arw16896_bbase <<<1, 256, 0, stream>>>(s);
    arw16896_part  <<<ARW_NT, 1024, 0, stream>>>(row, col, s);
    arw16896_pass2 <<<ARW_NB, 1024, 0, stream>>>(s);
    arw16896_walk  <<<(ARW_N_NODES + 255) / 256, 256, 0, stream>>>(ru, ei, s, o);
    arw16896_asm   <<<(ARW_N_EDGES / 4 + 255) / 256, 256, 0, stream>>>(ei, wgt, o);
}

// Round 9
// 228.419 us; speedup vs baseline: 1.0425x; 1.0425x over previous
//
#include <hip/hip_runtime.h>

// Problem constants
#define ARW_N_NODES   100000
#define ARW_N_EDGES   3200000
#define ARW_N_WALKERS 400000
#define ARW_WLEN      8
#define ARW_LOUT      7
#define ARW_ROW_LEN   6000000           // N_EDGES + N_WALKERS*LOUT
#define ARW_OUT_ELEMS 18000000          // float32 output elements

// Sort geometry: 256 buckets of 392 rows (b = r/392); 782 tiles of 4096 edges
// (781 full + 1 quarter). Big tiles -> part writes 64B-line runs per bucket
// (was 16B at 1024-tiles: 4x cross-XCD false-sharing on P).
#define ARW_NB    256
#define ARW_RPB   392
#define ARW_NT    782
#define ARW_TP    784                  // padded t-stride for Bt (b-major)
#define ARW_TILE  4096
#define ARW_PMAX  14336                // pass2 LDS P-stage capacity (bucket max ~13.0K)

// Scratch inside d_out (18M floats = 72MB), int32 view; staged lifetimes:
//   Ht  @ [0, 200192)          histograms, T-MAJOR: Ht[t][b] = HT + t*256 + b
//                              (thist writes 1KB coalesced runs per block)
//   Bt  @ [900000, 1100672)    bucket-LOCAL scan bases Bt[b][t] = BT + b*TP + t
//   tot @ [1750000, +256)      per-bucket totals (emitted by bscan2)
//   cb  @ [1760000, +256)      bucket exclusive bases (global)
//   pd  @ [1800000, 1900000)   packed (rowptr<<10 | deg), written by pass2
//   P   @ [6000000, 9200000)   packed partition (dead after pass2; walk's fused
//                              row1-copy overwrites it)
//   col_s @ [12000000, 15200000) (weights region; asm overwrites after walk)
// walk writes: targets [9200000,12000000), roots [3200000,6000000),
//              row1-originals [6000000,9200000).
// asm (last) writes [0,3200000) + [12000000,18000000).
#define ARW_HT    0
#define ARW_BT    900000
#define ARW_TOT   1750000
#define ARW_CB    1760000
#define ARW_PD    1800000
#define ARW_P     6000000
#define ARW_COLS  12000000

__global__ void AddRandomWalkEdge_16896401342869_kernel() {}

// ---------- 1. tile histogram: one 4096-tile/block, t-major coalesced output ----------
__global__ __launch_bounds__(1024) void arw16896_thist(const int* __restrict__ row,
                                                       int* __restrict__ s) {
    __shared__ int h[256];
    int tid = threadIdx.x, t = blockIdx.x;
    if (tid < 256) h[tid] = 0;
    __syncthreads();
    #pragma unroll
    for (int rnd = 0; rnd < 4; rnd++) {
        int e = t * ARW_TILE + rnd * 1024 + tid;
        if (e < ARW_N_EDGES) atomicAdd(&h[row[e] / ARW_RPB], 1);
    }
    __syncthreads();
    if (tid < 256) s[ARW_HT + t * 256 + tid] = h[tid];   // 1KB contiguous run
}

// ---------- 2a. per-bucket exclusive scan over 782 tiles (single chunk) + total ----------
__global__ __launch_bounds__(1024) void arw16896_bscan2(int* __restrict__ s) {
    __shared__ int wsum[16];
    int b = blockIdx.x, tid = threadIdx.x, lane = tid & 63, wid = tid >> 6;
    int v = (tid < ARW_NT) ? s[ARW_HT + tid * 256 + b] : 0;   // t-major gather (L2)
    int sv = v;
    #pragma unroll
    for (int off = 1; off < 64; off <<= 1) {
        int x = __shfl_up(sv, off, 64);
        if (lane >= off) sv += x;
    }
    if (lane == 63) wsum[wid] = sv;
    __syncthreads();
    int pre = 0, tot = 0;
    #pragma unroll
    for (int w = 0; w < 16; w++) {
        int x = wsum[w];
        if (w < wid) pre += x;
        tot += x;
    }
    if (tid < ARW_NT) s[ARW_BT + b * ARW_TP + tid] = pre + sv - v;  // bucket-local
    if (tid == 0) s[ARW_TOT + b] = tot;
}

// ---------- 2b. exclusive scan of 256 bucket totals (1 block) -> cb ----------
__global__ __launch_bounds__(256) void arw16896_bbase(int* __restrict__ s) {
    __shared__ int sm[256];
    int tid = threadIdx.x;
    int v = s[ARW_TOT + tid];
    sm[tid] = v;
    __syncthreads();
    for (int off = 1; off < 256; off <<= 1) {
        int x = 0;
        if (tid >= off) x = sm[tid - off];
        __syncthreads();
        sm[tid] += x;
        __syncthreads();
    }
    s[ARW_CB + tid] = sm[tid] - v;
}

// ---------- 3. stable partition, 4096-edge tiles (4 rounds + running cursor) ----------
// Per round: 8-bit ballot multisplit (in-wave rank) + cross-wave W table; runc
// carries bucket cursors across rounds (R1-pass2 pattern -> stable in e-order).
// Bucket runs are now ~16 edges = 64B: full-line writes, minimal false sharing.
__global__ __launch_bounds__(1024) void arw16896_part(const int* __restrict__ row,
                                                      const int* __restrict__ col,
                                                      int* __restrict__ s) {
    __shared__ unsigned short W[16 * 256];    // 8 KB
    __shared__ int runc[256], lbase[256];
    int tid  = threadIdx.x;
    int wave = tid >> 6, lane = tid & 63;
    int t = blockIdx.x;
    if (tid < 256) {
        runc[tid]  = 0;
        lbase[tid] = s[ARW_CB + tid] + s[ARW_BT + tid * ARW_TP + t];
    }
    __syncthreads();
    #pragma unroll
    for (int rnd = 0; rnd < 4; rnd++) {
        int e = t * ARW_TILE + rnd * 1024 + tid;
        int valid = (e < ARW_N_EDGES) ? 1 : 0;
        int r = valid ? row[e] : 0;
        int cv = valid ? col[e] : 0;
        int b = r / ARW_RPB;                 // magic-mul division
        int lr = r - b * ARW_RPB;            // 9 bits (<392)
        #pragma unroll
        for (int j = 0; j < 4; j++) W[tid + j * 1024] = 0;
        __syncthreads();
        unsigned long long mask = ~0ULL;
        #pragma unroll
        for (int bit = 0; bit < 8; bit++) {
            unsigned long long bal = __ballot((b >> bit) & 1);
            mask &= ((b >> bit) & 1) ? bal : ~bal;
        }
        mask &= __ballot(valid);
        int rankw = __popcll(mask & ((1ULL << lane) - 1ULL));
        if (valid) W[wave * 256 + b] = (unsigned short)__popcll(mask);
        __syncthreads();
        if (valid) {
            int cross = 0;
            for (int w2 = 0; w2 < 16; w2++) {
                if (w2 >= wave) break;
                cross += (int)W[w2 * 256 + b];
            }
            s[ARW_P + lbase[b] + runc[b] + cross + rankw] = (lr << 17) | cv;
        }
        __syncthreads();
        if (tid < 256) {
            int a = 0;
            #pragma unroll
            for (int w = 0; w < 16; w++) a += (int)W[w * 256 + tid];
            runc[tid] += a;
        }
        __syncthreads();
    }
}

// ---------- 4. per-bucket stable scatter -> col_s + packed pd (R7-proven) ----------
// Ballot multisplit; bucket's P window (<=56KB) staged in LDS once (kills the
// second 12.8MB global read). W shrunk to ushort (wave counts <= 64).
__global__ __launch_bounds__(1024) void arw16896_pass2(int* __restrict__ s) {
    __shared__ int PL[ARW_PMAX];              // 56 KB
    __shared__ unsigned short W[16 * 512];    // 16 KB
    __shared__ int hist[512], pref[512], runc[512];
    int tid = threadIdx.x, lane = tid & 63, wave = tid >> 6;
    int b = blockIdx.x;
    int start = s[ARW_CB + b];
    int end   = (b == ARW_NB - 1) ? ARW_N_EDGES : s[ARW_CB + b + 1];
    int cnt = end - start;
    int staged = cnt < ARW_PMAX ? cnt : ARW_PMAX;   // overflow ~16 sigma; guarded
    int rows0 = b * ARW_RPB;
    int nrows = ARW_N_NODES - rows0; if (nrows > ARW_RPB) nrows = ARW_RPB;

    for (int k = tid; k < staged; k += 1024) PL[k] = s[ARW_P + start + k];
    if (tid < 512) hist[tid] = 0;
    __syncthreads();

    // Pass A: histogram (from LDS)
    for (int k = tid; k < cnt; k += 1024) {
        unsigned p = (unsigned)(k < staged ? PL[k] : s[ARW_P + start + k]);
        atomicAdd(&hist[p >> 17], 1);
    }
    __syncthreads();
    if (tid < 512) pref[tid] = hist[tid];
    __syncthreads();
    for (int off = 1; off < 512; off <<= 1) {     // inclusive scan of hist
        int x = 0;
        if (tid < 512 && tid >= off) x = pref[tid - off];
        __syncthreads();
        if (tid < 512) pref[tid] += x;
        __syncthreads();
    }
    if (tid < 512) runc[tid] = 0;
    if (tid < nrows) {
        // packed (rowptr<<10 | deg). rowptr < 3.2M (22 bits); deg Poisson(32) << 1023.
        unsigned deg = (unsigned)hist[tid];
        unsigned rp  = (unsigned)(start + pref[tid] - hist[tid]);
        s[ARW_PD + rows0 + tid] = (int)((rp << 10) | deg);
    }
    __syncthreads();

    // Pass B: stable scatter (reads LDS)
    for (int c0 = 0; c0 < cnt; c0 += 1024) {
        int k = c0 + tid;
        int valid = (k < cnt) ? 1 : 0;
        unsigned p = 0u;
        if (valid) p = (unsigned)(k < staged ? PL[k] : s[ARW_P + start + k]);
        unsigned lr = p >> 17;                     // 9 bits
        #pragma unroll
        for (int j = 0; j < 8; j++) W[tid + j * 1024] = 0;
        __syncthreads();
        unsigned long long mask = ~0ULL;
        #pragma unroll
        for (int bit = 0; bit < 9; bit++) {
            unsigned long long bal = __ballot((lr >> bit) & 1u);
            mask &= ((lr >> bit) & 1u) ? bal : ~bal;
        }
        mask &= __ballot(valid);
        int rankw = __popcll(mask & ((1ULL << lane) - 1ULL));
        if (valid) W[wave * 512 + lr] = (unsigned short)__popcll(mask);
        __syncthreads();
        if (valid) {
            int cross = 0;
            for (int w2 = 0; w2 < 16; w2++) {
                if (w2 >= wave) break;
                cross += (int)W[w2 * 512 + lr];
            }
            int pos = start + (pref[lr] - hist[lr]) + runc[lr] + cross + rankw;
            s[ARW_COLS + pos] = (int)(p & 0x1FFFFu);
        }
        __syncthreads();
        if (tid < 512) {
            int a = 0;
            #pragma unroll
            for (int w = 0; w < 16; w++) a += (int)W[w * 512 + tid];
            runc[tid] += a;
        }
        __syncthreads();
    }
}

// ---------- 5. walks (256 thr) + fused streaming tail ----------
// Walk is miss-throughput bound (~36% HBM BW, VALU 3%): idle BW absorbs the
// row1-originals copy ([6M,9.2M), over dead P) and the roots fill ([3.2M,6M)).
__global__ __launch_bounds__(256) void arw16896_walk(const float* __restrict__ ru,
                                                     const int* __restrict__ ei,
                                                     const int* __restrict__ s,
                                                     float* __restrict__ o) {
    __shared__ float tg[4 * 256 * ARW_LOUT];   // 28 KB: 4 segments of 256x7
    int tid = threadIdx.x;
    int v = blockIdx.x * 256 + tid;
    if (v < ARW_N_NODES) {
        float uu[4][8];
        int cur[4];
        #pragma unroll
        for (int k = 0; k < 4; k++) {
            const float4* rp4 = (const float4*)(ru + (size_t)(v + k * ARW_N_NODES) * 8);
            float4 ra = rp4[0], rb = rp4[1];
            uu[k][0] = ra.x; uu[k][1] = ra.y; uu[k][2] = ra.z; uu[k][3] = ra.w;
            uu[k][4] = rb.x; uu[k][5] = rb.y; uu[k][6] = rb.z; uu[k][7] = rb.w;
        }
        // step 0: all 4 walkers share pd[v]; col loads hit the same row segment
        unsigned pd0 = (unsigned)s[ARW_PD + v];
        int d0  = (int)(pd0 & 1023u);
        int rp0 = (int)(pd0 >> 10);
        #pragma unroll
        for (int k = 0; k < 4; k++) {
            int off = (int)(uu[k][0] * (float)d0);   // f32 mul + trunc == reference
            if (off > d0 - 1) off = d0 - 1;
            int nxt = s[ARW_COLS + rp0 + off];       // off=-1 only if d0==0: in-bounds junk
            cur[k] = (d0 > 0) ? nxt : v;
        }
        // steps 1..7: 4 independent chains; batch the 4 pd loads, then 4 col loads
        #pragma unroll
        for (int t = 1; t < ARW_WLEN; t++) {
            unsigned pdk[4];
            #pragma unroll
            for (int k = 0; k < 4; k++) pdk[k] = (unsigned)s[ARW_PD + cur[k]];
            #pragma unroll
            for (int k = 0; k < 4; k++) {
                int d = (int)(pdk[k] & 1023u);
                int off = (int)(uu[k][t] * (float)d);
                if (off > d - 1) off = d - 1;        // d==0 -> off=-1, load stays in-bounds
                int nxt = s[ARW_COLS + (int)(pdk[k] >> 10) + off];
                cur[k] = (d > 0) ? nxt : cur[k];
                tg[k * (256 * ARW_LOUT) + tid * ARW_LOUT + (t - 1)] = (float)cur[k];
            }
        }
    }
    __syncthreads();
    int blkN = ARW_N_NODES - blockIdx.x * 256;
    if (blkN > 256) blkN = 256;
    int valid = blkN * ARW_LOUT;
    #pragma unroll
    for (int k = 0; k < 4; k++) {
        int base = ARW_ROW_LEN + ARW_N_EDGES +
                   (k * ARW_N_NODES + blockIdx.x * 256) * ARW_LOUT;
        for (int j = tid; j < valid; j += 256)
            o[base + j] = tg[k * (256 * ARW_LOUT) + j];
    }
    // fused streaming tail (grid-stride over all walk threads)
    int gid = blockIdx.x * 256 + tid;
    int stride = gridDim.x * 256;
    for (int i4 = gid; i4 < ARW_N_EDGES / 4; i4 += stride) {
        int4 r1 = ((const int4*)(ei + ARW_N_EDGES))[i4];
        ((float4*)(o + ARW_ROW_LEN))[i4] =
            make_float4((float)r1.x, (float)r1.y, (float)r1.z, (float)r1.w);
    }
    for (int i4 = gid; i4 < (ARW_N_WALKERS * ARW_LOUT) / 4; i4 += stride) {
        int i = i4 * 4;
        float4 r;
        r.x = (float)(((i    ) / ARW_LOUT) % ARW_N_NODES);
        r.y = (float)(((i + 1) / ARW_LOUT) % ARW_N_NODES);
        r.z = (float)(((i + 2) / ARW_LOUT) % ARW_N_NODES);
        r.w = (float)(((i + 3) / ARW_LOUT) % ARW_N_NODES);
        ((float4*)(o + ARW_N_EDGES))[i4] = r;
    }
}

// ---------- 6. remaining assembly: row0 originals + weights + ones ----------
__global__ __launch_bounds__(256) void arw16896_asm(const int* __restrict__ ei,
                                                    const float* __restrict__ wgt,
                                                    float* __restrict__ o) {
    int i4 = blockIdx.x * blockDim.x + threadIdx.x;
    if (i4 < ARW_N_EDGES / 4) {
        int4 r0 = ((const int4*)ei)[i4];
        float4 wv = ((const float4*)wgt)[i4];
        ((float4*)o)[i4] = make_float4((float)r0.x, (float)r0.y, (float)r0.z, (float)r0.w);
        ((float4*)(o + 2 * ARW_ROW_LEN))[i4] = wv;
    }
    if (i4 < (ARW_N_WALKERS * ARW_LOUT) / 4) {
        ((float4*)(o + 2 * ARW_ROW_LEN + ARW_N_EDGES))[i4] = make_float4(1.f, 1.f, 1.f, 1.f);
    }
}

extern "C" void kernel_launch(void* const* d_in, const int* in_sizes, int n_in,
                              void* d_out, int out_size, void* d_ws, size_t ws_size,
                              hipStream_t stream) {
    const int*   ei  = (const int*)d_in[0];
    const float* wgt = (const float*)d_in[1];
    const float* ru  = (const float*)d_in[2];
    int*   s = (int*)d_out;
    float* o = (float*)d_out;
    const int* row = ei;
    const int* col = ei + ARW_N_EDGES;

    arw16896_thist <<<ARW_NT, 1024, 0, stream>>>(row, s);
    arw16896_bscan2<<<ARW_NB, 1024, 0, stream>>>(s);
    arw16896_bbase <<<1, 256, 0, stream>>>(s);
    arw16896_part  <<<ARW_NT, 1024, 0, stream>>>(row, col, s);
    arw16896_pass2 <<<ARW_NB, 1024, 0, stream>>>(s);
    arw16896_walk  <<<(ARW_N_NODES + 255) / 256, 256, 0, stream>>>(ru, ei, s, o);
    arw16896_asm   <<<(ARW_N_EDGES / 4 + 255) / 256, 256, 0, stream>>>(ei, wgt, o);
}